// Round 7
// baseline (107.111 us; speedup 1.0000x reference)
//
#include <hip/hip_runtime.h>
#include <hip/hip_bf16.h>

#define B 16
#define N 10000
#define D 64
#define R 64
#define H 512
#define K 32
#define NBLK ((N + 255) / 256)       // 40 (k_rbf + k_norm grid)
#define NBUCK 4096

typedef unsigned long long ull;

// ---------- ws layout (bytes) ----------
// oidx   : B*K int     @ 0        (2048)
// ow     : B*K f32     @ 2048     (2048)
// tm     : B*K*D f32   @ 4096     (131072)
// nm2    : B*K f32     @ 135168   (-0.5*||mean||^2)
// part   : B*NBLK f32  @ 137216   (2560)
// rp     : B*H f32     @ 139776   (b1 + r_b @ W1[:, :R].T)

// ---------------- kernel 1: exact top-K set + r_part ----------------
__global__ __launch_bounds__(1024) void k_topk(const float* __restrict__ e,
                                               const float* __restrict__ rE,
                                               const float* __restrict__ W1,
                                               const float* __restrict__ b1,
                                               int* __restrict__ oidx,
                                               float* __restrict__ ow,
                                               float* __restrict__ rp) {
    const int b = blockIdx.x, tid = threadIdx.x;
    __shared__ unsigned hist[NBUCK];
    __shared__ ull cand[1024];
    __shared__ float rEs[R];
    __shared__ unsigned cnt;
    __shared__ int tsh;

    #pragma unroll
    for (int i = 0; i < NBUCK / 1024; ++i) hist[tid + i * 1024] = 0;
    if (tid == 0) cnt = 0;
    if (tid < R) rEs[tid] = rE[b * R + tid];

    ull keys[10];
    int bkt[10];
    #pragma unroll
    for (int i = 0; i < 10; ++i) {
        const int n = tid + i * 1024;
        keys[i] = 0ull; bkt[i] = -1;
        if (n < N) {
            const float v = e[b * N + n];
            keys[i] = ((ull)__float_as_uint(v) << 32) |
                      (unsigned)(0xFFFFFFFFu - (unsigned)n);
            int bu = (int)(v * (float)NBUCK);
            bkt[i] = bu > NBUCK - 1 ? NBUCK - 1 : (bu < 0 ? 0 : bu);
        }
    }
    __syncthreads();
    #pragma unroll
    for (int i = 0; i < 10; ++i) if (bkt[i] >= 0) atomicAdd(&hist[bkt[i]], 1u);
    __syncthreads();

    // wave 0: parallel suffix scan from the top, 64 buckets per step
    if (tid < 64) {
        unsigned acc = 0;
        for (int w = 0; w < NBUCK / 64; ++w) {
            const int j = NBUCK - 1 - (w * 64 + tid);
            unsigned p = hist[j];
            #pragma unroll
            for (int off = 1; off < 64; off <<= 1) {
                unsigned o = __shfl_up(p, off, 64);
                if (tid >= off) p += o;
            }
            const ull mask = __ballot(acc + p >= K);
            if (mask) {
                if (tid == 0) {
                    const int l0 = __ffsll((long long)mask) - 1;
                    tsh = NBUCK - 1 - (w * 64 + l0);
                }
                break;
            }
            acc += (unsigned)__shfl((int)p, 63, 64);
        }
    }
    __syncthreads();
    const int t = tsh;

    #pragma unroll
    for (int i = 0; i < 10; ++i)
        if (bkt[i] >= t) {
            unsigned p = atomicAdd(&cnt, 1u);
            if (p < 1024u) cand[p] = keys[i];
        }
    __syncthreads();

    const unsigned C = cnt < 1024u ? cnt : 1024u;
    if (tid < (int)C) {
        const ull mine = cand[tid];
        int rank = 0;
        for (unsigned j = 0; j < C; ++j) rank += (cand[j] > mine);
        if (rank < K) {
            oidx[b * K + rank] = (int)(0xFFFFFFFFu - (unsigned)(mine & 0xFFFFFFFFu));
            ow[b * K + rank] = __uint_as_float((unsigned)(mine >> 32));
        }
    }

    // r_part tail (independent of selection; rEs was written pre-barrier)
    if (tid < H) {
        const float4* w = (const float4*)(W1 + tid * (R + D));  // cols 0..R
        float acc = b1[tid];
        #pragma unroll
        for (int i = 0; i < R / 4; ++i) {
            const float4 wv = w[i];
            acc += wv.x * rEs[4 * i] + wv.y * rEs[4 * i + 1] +
                   wv.z * rEs[4 * i + 2] + wv.w * rEs[4 * i + 3];
        }
        rp[b * H + tid] = acc;
    }
}

// ---------------- kernel 2: MLP on selected rows (2 pairs/block) ----------------
__global__ __launch_bounds__(512) void k_means(
        const float* __restrict__ sup, const float* __restrict__ W1,
        const float* __restrict__ W2, const float* __restrict__ b2,
        const int* __restrict__ oidx, const float* __restrict__ rp,
        float* __restrict__ tm, float* __restrict__ nm2) {
    const int b = blockIdx.x >> 4, pr = blockIdx.x & 15;
    const int gk = b * K + pr * 2;
    const int tid = threadIdx.x;
    __shared__ float sA[D], sB[D];
    __shared__ float hA[H], hB[H];
    __shared__ float partA[512], partB[512];

    const int id0 = oidx[gk], id1 = oidx[gk + 1];
    if (tid < D) sA[tid] = sup[id0 * D + tid];
    else if (tid < 2 * D) sB[tid - D] = sup[id1 * D + (tid - D)];
    __syncthreads();

    {   // phase 1: one h-row per thread, weight row read once for both pairs
        const float4* w = (const float4*)(W1 + tid * (R + D) + R);
        float a0 = rp[b * H + tid], a1 = a0;
        #pragma unroll
        for (int i = 0; i < D / 4; ++i) {
            const float4 wv = w[i];
            a0 += wv.x * sA[4 * i] + wv.y * sA[4 * i + 1] +
                  wv.z * sA[4 * i + 2] + wv.w * sA[4 * i + 3];
            a1 += wv.x * sB[4 * i] + wv.y * sB[4 * i + 1] +
                  wv.z * sB[4 * i + 2] + wv.w * sB[4 * i + 3];
        }
        hA[tid] = fmaxf(a0, 0.f);
        hB[tid] = fmaxf(a1, 0.f);
    }
    __syncthreads();

    {   // phase 2: d = tid&63, 8 chunks of 64 over H
        const int d = tid & 63, ch = tid >> 6;
        const float4* w2 = (const float4*)(W2 + d * H + ch * 64);
        float a0 = 0.f, a1 = 0.f;
        #pragma unroll
        for (int i = 0; i < 16; ++i) {
            const float4 wv = w2[i];
            const int hb = ch * 64 + 4 * i;
            a0 += wv.x * hA[hb] + wv.y * hA[hb + 1] + wv.z * hA[hb + 2] + wv.w * hA[hb + 3];
            a1 += wv.x * hB[hb] + wv.y * hB[hb + 1] + wv.z * hB[hb + 2] + wv.w * hB[hb + 3];
        }
        partA[tid] = a0;
        partB[tid] = a1;
    }
    __syncthreads();

    if (tid < 128) {            // wave 0 -> pair 0, wave 1 -> pair 1
        const int d = tid & 63, w = tid >> 6;
        const float* part = w == 0 ? partA : partB;
        float m = b2[d];
        #pragma unroll
        for (int c = 0; c < 8; ++c) m += part[c * 64 + d];
        tm[(gk + w) * D + d] = m;
        float sq = m * m;
        #pragma unroll
        for (int off = 32; off > 0; off >>= 1) sq += __shfl_down(sq, off, 64);
        if (d == 0) nm2[gk + w] = -0.5f * sq;
    }
}

// ---------------- kernel 3: RBF, 4n x 8k register tile ----------------
// Block = 4 waves (one wave-uniform k-group of 8 each) x 64 lanes x 4 rows
// = 256 n x 32 k. m reads are broadcast ds_read_b128 amortized over 4 rows;
// s chunk register-resident. FMA : LDS-instr ~ 11:1.
__global__ __launch_bounds__(256) void k_rbf(
        const float* __restrict__ sup, const float* __restrict__ tm,
        const float* __restrict__ nm2, const float* __restrict__ ow,
        float* __restrict__ out, float* __restrict__ part) {
    const int b = blockIdx.y;
    const int tid = threadIdx.x;
    const int lane = tid & 63;
    const int kg = tid >> 6;                 // wave-uniform k-group (8 k)
    const int nb = blockIdx.x * 256;
    __shared__ float4 stm[K * 16];           // tm[b] as [k][16] float4, 8KB
    __shared__ float sw[K], snm2[K];
    __shared__ float4 red4[4][64];           // per-kgroup row totals
    __shared__ float wpart[4];

    const float4* tm4 = (const float4*)(tm + b * K * D);
    stm[tid] = tm4[tid];
    stm[tid + 256] = tm4[tid + 256];
    if (tid < K) { sw[tid] = ow[b * K + tid]; snm2[tid] = nm2[b * K + tid]; }
    __syncthreads();

    const int r0 = nb + 4 * lane;            // this thread's 4 rows
    int rows[4];
    #pragma unroll
    for (int i = 0; i < 4; ++i) rows[i] = (r0 + i) < N ? (r0 + i) : (N - 1);

    float acc[4][8];
    #pragma unroll
    for (int i = 0; i < 4; ++i)
        #pragma unroll
        for (int j = 0; j < 8; ++j) acc[i][j] = 0.f;
    float s2[4] = {0.f, 0.f, 0.f, 0.f};

    #pragma unroll
    for (int dc = 0; dc < 4; ++dc) {         // 4 chunks of 16 d
        float4 s[4][4];
        #pragma unroll
        for (int i = 0; i < 4; ++i) {
            const float4* sp = (const float4*)(sup + rows[i] * D) + dc * 4;
            #pragma unroll
            for (int e = 0; e < 4; ++e) s[i][e] = sp[e];
            #pragma unroll
            for (int e = 0; e < 4; ++e)
                s2[i] += s[i][e].x * s[i][e].x + s[i][e].y * s[i][e].y +
                         s[i][e].z * s[i][e].z + s[i][e].w * s[i][e].w;
        }
        #pragma unroll
        for (int kk = 0; kk < 8; ++kk) {
            const float4* mp = &stm[(kg * 8 + kk) * 16 + dc * 4];
            const float4 m0 = mp[0], m1 = mp[1], m2 = mp[2], m3 = mp[3];
            #pragma unroll
            for (int i = 0; i < 4; ++i) {
                acc[i][kk] += s[i][0].x * m0.x + s[i][0].y * m0.y +
                              s[i][0].z * m0.z + s[i][0].w * m0.w +
                              s[i][1].x * m1.x + s[i][1].y * m1.y +
                              s[i][1].z * m1.z + s[i][1].w * m1.w +
                              s[i][2].x * m2.x + s[i][2].y * m2.y +
                              s[i][2].z * m2.z + s[i][2].w * m2.w +
                              s[i][3].x * m3.x + s[i][3].y * m3.y +
                              s[i][3].z * m3.z + s[i][3].w * m3.w;
            }
        }
    }

    float tot[4];
    #pragma unroll
    for (int i = 0; i < 4; ++i) {
        const float ns2 = -0.5f * s2[i];
        float t = 0.f;
        #pragma unroll
        for (int kk = 0; kk < 8; ++kk)
            t += sw[kg * 8 + kk] * __expf(ns2 + snm2[kg * 8 + kk] + acc[i][kk]);
        tot[i] = (r0 + i) < N ? t : 0.f;
    }
    red4[kg][lane] = make_float4(tot[0], tot[1], tot[2], tot[3]);
    __syncthreads();

    // combine k-groups: thread t owns local row t
    const float* redf = (const float*)red4;
    float v = redf[tid] + redf[256 + tid] + redf[512 + tid] + redf[768 + tid];
    const int n = nb + tid;
    if (n < N) out[b * N + n] = v;
    else v = 0.f;

    #pragma unroll
    for (int off = 32; off > 0; off >>= 1) v += __shfl_down(v, off, 64);
    if ((tid & 63) == 0) wpart[tid >> 6] = v;
    __syncthreads();
    if (tid == 0)
        part[b * NBLK + blockIdx.x] = (wpart[0] + wpart[1]) + (wpart[2] + wpart[3]);
}

// ---------------- kernel 4: normalize ----------------
__global__ void k_norm(float* __restrict__ out, const float* __restrict__ part) {
    const int b = blockIdx.y;
    const int n = blockIdx.x * 256 + threadIdx.x;
    const int tid = threadIdx.x;
    __shared__ float sdiv;
    if (tid < 64) {
        float v = (tid < NBLK) ? part[b * NBLK + tid] : 0.f;
        #pragma unroll
        for (int off = 32; off > 0; off >>= 1) v += __shfl_down(v, off, 64);
        if (tid == 0) sdiv = 1.f / (v + 1e-10f);
    }
    __syncthreads();
    if (n < N) out[b * N + n] *= sdiv;
}

extern "C" void kernel_launch(void* const* d_in, const int* in_sizes, int n_in,
                              void* d_out, int out_size, void* d_ws, size_t ws_size,
                              hipStream_t stream) {
    const float* e   = (const float*)d_in[0];
    const float* rE  = (const float*)d_in[1];
    const float* sup = (const float*)d_in[2];
    const float* W1  = (const float*)d_in[3];
    const float* b1  = (const float*)d_in[4];
    const float* W2  = (const float*)d_in[5];
    const float* b2  = (const float*)d_in[6];
    float* out = (float*)d_out;

    char* ws = (char*)d_ws;
    int*   oidx = (int*)(ws + 0);
    float* ow   = (float*)(ws + 2048);
    float* tm   = (float*)(ws + 4096);
    float* nm2  = (float*)(ws + 135168);
    float* part = (float*)(ws + 137216);
    float* rp   = (float*)(ws + 139776);

    hipLaunchKernelGGL(k_topk, dim3(B), dim3(1024), 0, stream,
                       e, rE, W1, b1, oidx, ow, rp);
    hipLaunchKernelGGL(k_means, dim3(B * 16), dim3(512), 0, stream,
                       sup, W1, W2, b2, oidx, rp, tm, nm2);
    hipLaunchKernelGGL(k_rbf, dim3(NBLK, B), dim3(256), 0, stream,
                       sup, tm, nm2, ow, out, part);
    hipLaunchKernelGGL(k_norm, dim3(NBLK, B), dim3(256), 0, stream, out, part);
}

// Round 8
// 56.338 us; speedup vs baseline: 1.9012x; 1.9012x over previous
//
#include <hip/hip_runtime.h>
#include <hip/hip_bf16.h>

#define B 16
#define N 10000
#define D 64
#define R 64
#define H 512
#define K 32
#define NBLK ((N + 255) / 256)       // 40 (k_rbf + k_norm grid)
#define NBUCK 4096

typedef unsigned long long ull;

// ---------- ws layout (bytes) ----------
// oidx   : B*K int     @ 0        (2048)
// ow     : B*K f32     @ 2048     (2048)
// tm     : B*K*D f32   @ 4096     (131072)
// nm2    : B*K f32     @ 135168   (-0.5*||mean||^2)
// part   : B*NBLK f32  @ 137216   (2560)
// rp     : B*H f32     @ 139776   (b1 + r_b @ W1[:, :R].T)

// ---------------- kernel 1: exact top-K set + r_part ----------------
__global__ __launch_bounds__(1024) void k_topk(const float* __restrict__ e,
                                               const float* __restrict__ rE,
                                               const float* __restrict__ W1,
                                               const float* __restrict__ b1,
                                               int* __restrict__ oidx,
                                               float* __restrict__ ow,
                                               float* __restrict__ rp) {
    const int b = blockIdx.x, tid = threadIdx.x;
    __shared__ unsigned hist[NBUCK];
    __shared__ ull cand[1024];
    __shared__ float rEs[R];
    __shared__ unsigned cnt;
    __shared__ int tsh;

    #pragma unroll
    for (int i = 0; i < NBUCK / 1024; ++i) hist[tid + i * 1024] = 0;
    if (tid == 0) cnt = 0;
    if (tid < R) rEs[tid] = rE[b * R + tid];

    ull keys[10];
    int bkt[10];
    #pragma unroll
    for (int i = 0; i < 10; ++i) {
        const int n = tid + i * 1024;
        keys[i] = 0ull; bkt[i] = -1;
        if (n < N) {
            const float v = e[b * N + n];
            keys[i] = ((ull)__float_as_uint(v) << 32) |
                      (unsigned)(0xFFFFFFFFu - (unsigned)n);
            int bu = (int)(v * (float)NBUCK);
            bkt[i] = bu > NBUCK - 1 ? NBUCK - 1 : (bu < 0 ? 0 : bu);
        }
    }
    __syncthreads();
    #pragma unroll
    for (int i = 0; i < 10; ++i) if (bkt[i] >= 0) atomicAdd(&hist[bkt[i]], 1u);
    __syncthreads();

    // wave 0: parallel suffix scan from the top, 64 buckets per step
    if (tid < 64) {
        unsigned acc = 0;
        for (int w = 0; w < NBUCK / 64; ++w) {
            const int j = NBUCK - 1 - (w * 64 + tid);
            unsigned p = hist[j];
            #pragma unroll
            for (int off = 1; off < 64; off <<= 1) {
                unsigned o = __shfl_up(p, off, 64);
                if (tid >= off) p += o;
            }
            const ull mask = __ballot(acc + p >= K);
            if (mask) {
                if (tid == 0) {
                    const int l0 = __ffsll((long long)mask) - 1;
                    tsh = NBUCK - 1 - (w * 64 + l0);
                }
                break;
            }
            acc += (unsigned)__shfl((int)p, 63, 64);
        }
    }
    __syncthreads();
    const int t = tsh;

    #pragma unroll
    for (int i = 0; i < 10; ++i)
        if (bkt[i] >= t) {
            unsigned p = atomicAdd(&cnt, 1u);
            if (p < 1024u) cand[p] = keys[i];
        }
    __syncthreads();

    const unsigned C = cnt < 1024u ? cnt : 1024u;
    if (tid < (int)C) {
        const ull mine = cand[tid];
        int rank = 0;
        for (unsigned j = 0; j < C; ++j) rank += (cand[j] > mine);
        if (rank < K) {
            oidx[b * K + rank] = (int)(0xFFFFFFFFu - (unsigned)(mine & 0xFFFFFFFFu));
            ow[b * K + rank] = __uint_as_float((unsigned)(mine >> 32));
        }
    }

    // r_part tail (independent of selection; rEs was written pre-barrier)
    if (tid < H) {
        const float4* w = (const float4*)(W1 + tid * (R + D));  // cols 0..R
        float acc = b1[tid];
        #pragma unroll
        for (int i = 0; i < R / 4; ++i) {
            const float4 wv = w[i];
            acc += wv.x * rEs[4 * i] + wv.y * rEs[4 * i + 1] +
                   wv.z * rEs[4 * i + 2] + wv.w * rEs[4 * i + 3];
        }
        rp[b * H + tid] = acc;
    }
}

// ---------------- kernel 2: MLP on selected rows (2 pairs/block) ----------------
__global__ __launch_bounds__(512) void k_means(
        const float* __restrict__ sup, const float* __restrict__ W1,
        const float* __restrict__ W2, const float* __restrict__ b2,
        const int* __restrict__ oidx, const float* __restrict__ rp,
        float* __restrict__ tm, float* __restrict__ nm2) {
    const int b = blockIdx.x >> 4, pr = blockIdx.x & 15;
    const int gk = b * K + pr * 2;
    const int tid = threadIdx.x;
    __shared__ float sA[D], sB[D];
    __shared__ float hA[H], hB[H];
    __shared__ float partA[512], partB[512];

    const int id0 = oidx[gk], id1 = oidx[gk + 1];
    if (tid < D) sA[tid] = sup[id0 * D + tid];
    else if (tid < 2 * D) sB[tid - D] = sup[id1 * D + (tid - D)];
    __syncthreads();

    {   // phase 1: one h-row per thread, weight row read once for both pairs
        const float4* w = (const float4*)(W1 + tid * (R + D) + R);
        float a0 = rp[b * H + tid], a1 = a0;
        #pragma unroll
        for (int i = 0; i < D / 4; ++i) {
            const float4 wv = w[i];
            a0 += wv.x * sA[4 * i] + wv.y * sA[4 * i + 1] +
                  wv.z * sA[4 * i + 2] + wv.w * sA[4 * i + 3];
            a1 += wv.x * sB[4 * i] + wv.y * sB[4 * i + 1] +
                  wv.z * sB[4 * i + 2] + wv.w * sB[4 * i + 3];
        }
        hA[tid] = fmaxf(a0, 0.f);
        hB[tid] = fmaxf(a1, 0.f);
    }
    __syncthreads();

    {   // phase 2: d = tid&63, 8 chunks of 64 over H
        const int d = tid & 63, ch = tid >> 6;
        const float4* w2 = (const float4*)(W2 + d * H + ch * 64);
        float a0 = 0.f, a1 = 0.f;
        #pragma unroll
        for (int i = 0; i < 16; ++i) {
            const float4 wv = w2[i];
            const int hb = ch * 64 + 4 * i;
            a0 += wv.x * hA[hb] + wv.y * hA[hb + 1] + wv.z * hA[hb + 2] + wv.w * hA[hb + 3];
            a1 += wv.x * hB[hb] + wv.y * hB[hb + 1] + wv.z * hB[hb + 2] + wv.w * hB[hb + 3];
        }
        partA[tid] = a0;
        partB[tid] = a1;
    }
    __syncthreads();

    if (tid < 128) {            // wave 0 -> pair 0, wave 1 -> pair 1
        const int d = tid & 63, w = tid >> 6;
        const float* part = w == 0 ? partA : partB;
        float m = b2[d];
        #pragma unroll
        for (int c = 0; c < 8; ++c) m += part[c * 64 + d];
        tm[(gk + w) * D + d] = m;
        float sq = m * m;
        #pragma unroll
        for (int off = 32; off > 0; off >>= 1) sq += __shfl_down(sq, off, 64);
        if (d == 0) nm2[gk + w] = -0.5f * sq;
    }
}

// ---------------- kernel 3: RBF, 4n x 8k register tile, spill-proof ----------------
// Block = 4 waves; wave kg owns k in [8kg, 8kg+8). Lane l owns rows
// nb + {0,64,128,192} + l. d is walked in 8-float sub-chunks with unroll 1
// so only s[4][2] (32 regs) + acc[4][8] (32) are live -> no spills.
// m reads are wave-uniform ds_read_b128 broadcasts amortized over 4 rows.
__global__ __launch_bounds__(256) void k_rbf(
        const float* __restrict__ sup, const float* __restrict__ tm,
        const float* __restrict__ nm2, const float* __restrict__ ow,
        float* __restrict__ out, float* __restrict__ part) {
    const int b = blockIdx.y;
    const int tid = threadIdx.x;
    const int lane = tid & 63;
    const int kg = tid >> 6;                 // wave-uniform k-group (8 k)
    const int nb = blockIdx.x * 256;
    __shared__ float4 stm[K * 16];           // tm[b] as [k][16] float4, 8KB
    __shared__ float sw[K], snm2[K];
    __shared__ float red[4][4][64];          // [kgroup][rowchunk][lane]
    __shared__ float wpart[4];

    const float4* tm4 = (const float4*)(tm + b * K * D);
    stm[tid] = tm4[tid];
    stm[tid + 256] = tm4[tid + 256];
    if (tid < K) { sw[tid] = ow[b * K + tid]; snm2[tid] = nm2[b * K + tid]; }
    __syncthreads();

    int rows[4];
    #pragma unroll
    for (int i = 0; i < 4; ++i) {
        const int r = nb + i * 64 + lane;
        rows[i] = r < N ? r : N - 1;         // clamp; zeroed in epilogue
    }

    float acc[4][8];
    #pragma unroll
    for (int i = 0; i < 4; ++i)
        #pragma unroll
        for (int j = 0; j < 8; ++j) acc[i][j] = 0.f;
    float s2[4] = {0.f, 0.f, 0.f, 0.f};

    #pragma unroll 1
    for (int dc = 0; dc < 8; ++dc) {         // 8 d per iteration
        float4 s[4][2];
        #pragma unroll
        for (int i = 0; i < 4; ++i) {
            const float4* sp = (const float4*)(sup + rows[i] * D + dc * 8);
            s[i][0] = sp[0];
            s[i][1] = sp[1];
            s2[i] += s[i][0].x * s[i][0].x + s[i][0].y * s[i][0].y +
                     s[i][0].z * s[i][0].z + s[i][0].w * s[i][0].w +
                     s[i][1].x * s[i][1].x + s[i][1].y * s[i][1].y +
                     s[i][1].z * s[i][1].z + s[i][1].w * s[i][1].w;
        }
        #pragma unroll
        for (int kk = 0; kk < 8; ++kk) {
            const float4* mp = &stm[(kg * 8 + kk) * 16 + dc * 2];
            const float4 m0 = mp[0], m1 = mp[1];
            #pragma unroll
            for (int i = 0; i < 4; ++i) {
                acc[i][kk] += s[i][0].x * m0.x + s[i][0].y * m0.y +
                              s[i][0].z * m0.z + s[i][0].w * m0.w +
                              s[i][1].x * m1.x + s[i][1].y * m1.y +
                              s[i][1].z * m1.z + s[i][1].w * m1.w;
            }
        }
    }

    #pragma unroll
    for (int i = 0; i < 4; ++i) {
        const float ns2 = -0.5f * s2[i];
        float t = 0.f;
        #pragma unroll
        for (int kk = 0; kk < 8; ++kk)
            t += sw[kg * 8 + kk] * __expf(ns2 + snm2[kg * 8 + kk] + acc[i][kk]);
        red[kg][i][lane] = (nb + i * 64 + lane) < N ? t : 0.f;
    }
    __syncthreads();

    // thread tid owns row nb + tid = nb + (tid>>6)*64 + (tid&63)
    const int rc = tid >> 6, rl = tid & 63;
    float v = red[0][rc][rl] + red[1][rc][rl] + red[2][rc][rl] + red[3][rc][rl];
    const int n = nb + tid;
    if (n < N) out[b * N + n] = v;
    else v = 0.f;

    #pragma unroll
    for (int off = 32; off > 0; off >>= 1) v += __shfl_down(v, off, 64);
    if ((tid & 63) == 0) wpart[tid >> 6] = v;
    __syncthreads();
    if (tid == 0)
        part[b * NBLK + blockIdx.x] = (wpart[0] + wpart[1]) + (wpart[2] + wpart[3]);
}

// ---------------- kernel 4: normalize ----------------
__global__ void k_norm(float* __restrict__ out, const float* __restrict__ part) {
    const int b = blockIdx.y;
    const int n = blockIdx.x * 256 + threadIdx.x;
    const int tid = threadIdx.x;
    __shared__ float sdiv;
    if (tid < 64) {
        float v = (tid < NBLK) ? part[b * NBLK + tid] : 0.f;
        #pragma unroll
        for (int off = 32; off > 0; off >>= 1) v += __shfl_down(v, off, 64);
        if (tid == 0) sdiv = 1.f / (v + 1e-10f);
    }
    __syncthreads();
    if (n < N) out[b * N + n] *= sdiv;
}

extern "C" void kernel_launch(void* const* d_in, const int* in_sizes, int n_in,
                              void* d_out, int out_size, void* d_ws, size_t ws_size,
                              hipStream_t stream) {
    const float* e   = (const float*)d_in[0];
    const float* rE  = (const float*)d_in[1];
    const float* sup = (const float*)d_in[2];
    const float* W1  = (const float*)d_in[3];
    const float* b1  = (const float*)d_in[4];
    const float* W2  = (const float*)d_in[5];
    const float* b2  = (const float*)d_in[6];
    float* out = (float*)d_out;

    char* ws = (char*)d_ws;
    int*   oidx = (int*)(ws + 0);
    float* ow   = (float*)(ws + 2048);
    float* tm   = (float*)(ws + 4096);
    float* nm2  = (float*)(ws + 135168);
    float* part = (float*)(ws + 137216);
    float* rp   = (float*)(ws + 139776);

    hipLaunchKernelGGL(k_topk, dim3(B), dim3(1024), 0, stream,
                       e, rE, W1, b1, oidx, ow, rp);
    hipLaunchKernelGGL(k_means, dim3(B * 16), dim3(512), 0, stream,
                       sup, W1, W2, b2, oidx, rp, tm, nm2);
    hipLaunchKernelGGL(k_rbf, dim3(NBLK, B), dim3(256), 0, stream,
                       sup, tm, nm2, ow, out, part);
    hipLaunchKernelGGL(k_norm, dim3(NBLK, B), dim3(256), 0, stream, out, part);
}

// Round 9
// 47.347 us; speedup vs baseline: 2.2623x; 1.1899x over previous
//
#include <hip/hip_runtime.h>
#include <hip/hip_bf16.h>

#define B 16
#define N 10000
#define D 64
#define R 64
#define H 512
#define K 32
#define NBLK ((N + 255) / 256)       // 40 (k_norm grid)
#define NPART 157                    // k_rbf grid x: 157 * 64 rows >= 10000
#define NBUCK 4096

typedef unsigned long long ull;
typedef short s16x8 __attribute__((ext_vector_type(8)));
typedef float f32x4 __attribute__((ext_vector_type(4)));

// ---------- ws layout (bytes) ----------
// oidx : B*K int      @ 0        (2048)
// ow   : B*K f32      @ 2048     (2048)
// nm2  : B*K f32      @ 4096     (2048)   -0.5*||mean||^2
// rp   : B*H f32      @ 6144     (32768)  b1 + r_b @ W1[:, :R].T
// tmh  : B*K*D bf16   @ 38912    (65536)  mean hi
// tml  : B*K*D bf16   @ 104448   (65536)  mean lo
// suph : N*D bf16     @ 169984   (1280000)
// supl : N*D bf16     @ 1449984  (1280000)
// nss  : N f32        @ 2729984  (40000)  -0.5*||s_n||^2
// part : B*NPART f32  @ 2769984  (10048)

static __device__ __forceinline__ ushort f2bf_bits(float x) {
    __hip_bfloat16 h = __float2bfloat16(x);
    return *reinterpret_cast<ushort*>(&h);
}
static __device__ __forceinline__ float bf_hi_f(float x) {
    return __bfloat162float(__float2bfloat16(x));
}

// ---------------- kernel 0: split sup into bf16 hi/lo + row norms ----------------
// block = 4 waves, one row per wave (64 d = 64 lanes). grid 2500 = N/4.
__global__ __launch_bounds__(256) void k_prep(const float* __restrict__ sup,
                                              ushort* __restrict__ suph,
                                              ushort* __restrict__ supl,
                                              float* __restrict__ nss) {
    const int row = blockIdx.x * 4 + (threadIdx.x >> 6);
    const int d = threadIdx.x & 63;
    const float v = sup[row * D + d];
    const float hf = bf_hi_f(v);
    suph[row * D + d] = f2bf_bits(v);
    supl[row * D + d] = f2bf_bits(v - hf);
    float s = v * v;
    #pragma unroll
    for (int off = 32; off > 0; off >>= 1) s += __shfl_xor(s, off, 64);
    if (d == 0) nss[row] = -0.5f * s;
}

// ---------------- kernel 1: exact top-K set + r_part ----------------
__global__ __launch_bounds__(1024) void k_topk(const float* __restrict__ e,
                                               const float* __restrict__ rE,
                                               const float* __restrict__ W1,
                                               const float* __restrict__ b1,
                                               int* __restrict__ oidx,
                                               float* __restrict__ ow,
                                               float* __restrict__ rp) {
    const int b = blockIdx.x, tid = threadIdx.x;
    __shared__ unsigned hist[NBUCK];
    __shared__ ull cand[1024];
    __shared__ float rEs[R];
    __shared__ unsigned cnt;
    __shared__ int tsh;

    #pragma unroll
    for (int i = 0; i < NBUCK / 1024; ++i) hist[tid + i * 1024] = 0;
    if (tid == 0) cnt = 0;
    if (tid < R) rEs[tid] = rE[b * R + tid];

    ull keys[10];
    int bkt[10];
    #pragma unroll
    for (int i = 0; i < 10; ++i) {
        const int n = tid + i * 1024;
        keys[i] = 0ull; bkt[i] = -1;
        if (n < N) {
            const float v = e[b * N + n];
            keys[i] = ((ull)__float_as_uint(v) << 32) |
                      (unsigned)(0xFFFFFFFFu - (unsigned)n);
            int bu = (int)(v * (float)NBUCK);
            bkt[i] = bu > NBUCK - 1 ? NBUCK - 1 : (bu < 0 ? 0 : bu);
        }
    }
    __syncthreads();
    #pragma unroll
    for (int i = 0; i < 10; ++i) if (bkt[i] >= 0) atomicAdd(&hist[bkt[i]], 1u);
    __syncthreads();

    // wave 0: parallel suffix scan from the top, 64 buckets per step
    if (tid < 64) {
        unsigned acc = 0;
        for (int w = 0; w < NBUCK / 64; ++w) {
            const int j = NBUCK - 1 - (w * 64 + tid);
            unsigned p = hist[j];
            #pragma unroll
            for (int off = 1; off < 64; off <<= 1) {
                unsigned o = __shfl_up(p, off, 64);
                if (tid >= off) p += o;
            }
            const ull mask = __ballot(acc + p >= K);
            if (mask) {
                if (tid == 0) {
                    const int l0 = __ffsll((long long)mask) - 1;
                    tsh = NBUCK - 1 - (w * 64 + l0);
                }
                break;
            }
            acc += (unsigned)__shfl((int)p, 63, 64);
        }
    }
    __syncthreads();
    const int t = tsh;

    #pragma unroll
    for (int i = 0; i < 10; ++i)
        if (bkt[i] >= t) {
            unsigned p = atomicAdd(&cnt, 1u);
            if (p < 1024u) cand[p] = keys[i];
        }
    __syncthreads();

    const unsigned C = cnt < 1024u ? cnt : 1024u;
    if (tid < (int)C) {
        const ull mine = cand[tid];
        int rank = 0;
        for (unsigned j = 0; j < C; ++j) rank += (cand[j] > mine);
        if (rank < K) {
            oidx[b * K + rank] = (int)(0xFFFFFFFFu - (unsigned)(mine & 0xFFFFFFFFu));
            ow[b * K + rank] = __uint_as_float((unsigned)(mine >> 32));
        }
    }

    // r_part tail (independent of selection; rEs was written pre-barrier)
    if (tid < H) {
        const float4* w = (const float4*)(W1 + tid * (R + D));  // cols 0..R
        float acc = b1[tid];
        #pragma unroll
        for (int i = 0; i < R / 4; ++i) {
            const float4 wv = w[i];
            acc += wv.x * rEs[4 * i] + wv.y * rEs[4 * i + 1] +
                   wv.z * rEs[4 * i + 2] + wv.w * rEs[4 * i + 3];
        }
        rp[b * H + tid] = acc;
    }
}

// ---------------- kernel 2: MLP on selected rows (2 pairs/block) ----------------
// writes mean as bf16 hi/lo (for MFMA) + nm2 = -0.5*||mean||^2 (f32, exact).
__global__ __launch_bounds__(512) void k_means(
        const float* __restrict__ sup, const float* __restrict__ W1,
        const float* __restrict__ W2, const float* __restrict__ b2,
        const int* __restrict__ oidx, const float* __restrict__ rp,
        ushort* __restrict__ tmh, ushort* __restrict__ tml,
        float* __restrict__ nm2) {
    const int b = blockIdx.x >> 4, pr = blockIdx.x & 15;
    const int gk = b * K + pr * 2;
    const int tid = threadIdx.x;
    __shared__ float sA[D], sB[D];
    __shared__ float hA[H], hB[H];
    __shared__ float partA[512], partB[512];

    const int id0 = oidx[gk], id1 = oidx[gk + 1];
    if (tid < D) sA[tid] = sup[id0 * D + tid];
    else if (tid < 2 * D) sB[tid - D] = sup[id1 * D + (tid - D)];
    __syncthreads();

    {   // phase 1: one h-row per thread, weight row read once for both pairs
        const float4* w = (const float4*)(W1 + tid * (R + D) + R);
        float a0 = rp[b * H + tid], a1 = a0;
        #pragma unroll
        for (int i = 0; i < D / 4; ++i) {
            const float4 wv = w[i];
            a0 += wv.x * sA[4 * i] + wv.y * sA[4 * i + 1] +
                  wv.z * sA[4 * i + 2] + wv.w * sA[4 * i + 3];
            a1 += wv.x * sB[4 * i] + wv.y * sB[4 * i + 1] +
                  wv.z * sB[4 * i + 2] + wv.w * sB[4 * i + 3];
        }
        hA[tid] = fmaxf(a0, 0.f);
        hB[tid] = fmaxf(a1, 0.f);
    }
    __syncthreads();

    {   // phase 2: d = tid&63, 8 chunks of 64 over H
        const int d = tid & 63, ch = tid >> 6;
        const float4* w2 = (const float4*)(W2 + d * H + ch * 64);
        float a0 = 0.f, a1 = 0.f;
        #pragma unroll
        for (int i = 0; i < 16; ++i) {
            const float4 wv = w2[i];
            const int hb = ch * 64 + 4 * i;
            a0 += wv.x * hA[hb] + wv.y * hA[hb + 1] + wv.z * hA[hb + 2] + wv.w * hA[hb + 3];
            a1 += wv.x * hB[hb] + wv.y * hB[hb + 1] + wv.z * hB[hb + 2] + wv.w * hB[hb + 3];
        }
        partA[tid] = a0;
        partB[tid] = a1;
    }
    __syncthreads();

    if (tid < 128) {            // wave 0 -> pair 0, wave 1 -> pair 1
        const int d = tid & 63, w = tid >> 6;
        const float* part = w == 0 ? partA : partB;
        float m = b2[d];
        #pragma unroll
        for (int c = 0; c < 8; ++c) m += part[c * 64 + d];
        const float hf = bf_hi_f(m);
        tmh[(gk + w) * D + d] = f2bf_bits(m);
        tml[(gk + w) * D + d] = f2bf_bits(m - hf);
        float sq = m * m;
        #pragma unroll
        for (int off = 32; off > 0; off >>= 1) sq += __shfl_down(sq, off, 64);
        if (d == 0) nm2[gk + w] = -0.5f * sq;
    }
}

// ---------------- kernel 3: RBF via split-bf16 MFMA ----------------
// block = 4 waves x 16 rows = 64 n-rows, one b. Per wave: C[16n x 32k] via
// 2 coltiles x 2 d-steps x 3 split products = 12 mfma_f32_16x16x32_bf16.
// A[row][kk]: row=lane&15, kk=(lane>>4)*8+j (16B load). B[kk][col]: col=lane&15,
// same kk (16B load). C/D: col=lane&15, row=(lane>>4)*4+j (verified layout).
// Epilogue: val = w_k * exp(nss[row] + nm2[k] + dot), row-sum via 16-lane
// butterfly, out + per-block partial for normalization.
__global__ __launch_bounds__(256) void k_rbf(
        const ushort* __restrict__ suph, const ushort* __restrict__ supl,
        const ushort* __restrict__ tmh, const ushort* __restrict__ tml,
        const float* __restrict__ nss, const float* __restrict__ nm2,
        const float* __restrict__ ow,
        float* __restrict__ out, float* __restrict__ part) {
    const int b = blockIdx.y;
    const int tid = threadIdx.x;
    const int lane = tid & 63;
    const int wt = tid >> 6;
    const int nb = blockIdx.x * 64;
    const int g = lane >> 4;
    const int c = lane & 15;
    __shared__ float wred[4];

    // A fragments (s rows, hi/lo), d-steps 0 and 1
    const int arow = nb + wt * 16 + c;
    const int arowc = arow < N ? arow : N - 1;
    const ushort* pah = suph + arowc * D + g * 8;
    const ushort* pal = supl + arowc * D + g * 8;
    const s16x8 ah0 = *(const s16x8*)(pah);
    const s16x8 ah1 = *(const s16x8*)(pah + 32);
    const s16x8 al0 = *(const s16x8*)(pal);
    const s16x8 al1 = *(const s16x8*)(pal + 32);

    // B fragments (m cols): coltile 0 -> k=c, coltile 1 -> k=16+c
    const ushort* pb0h = tmh + (b * K + c) * D + g * 8;
    const ushort* pb0l = tml + (b * K + c) * D + g * 8;
    const ushort* pb1h = pb0h + 16 * D;
    const ushort* pb1l = pb0l + 16 * D;
    const s16x8 b0h0 = *(const s16x8*)(pb0h);
    const s16x8 b0h1 = *(const s16x8*)(pb0h + 32);
    const s16x8 b0l0 = *(const s16x8*)(pb0l);
    const s16x8 b0l1 = *(const s16x8*)(pb0l + 32);
    const s16x8 b1h0 = *(const s16x8*)(pb1h);
    const s16x8 b1h1 = *(const s16x8*)(pb1h + 32);
    const s16x8 b1l0 = *(const s16x8*)(pb1l);
    const s16x8 b1l1 = *(const s16x8*)(pb1l + 32);

    f32x4 acc0 = {0.f, 0.f, 0.f, 0.f};
    f32x4 acc1 = {0.f, 0.f, 0.f, 0.f};
    // hi*hi + hi*lo + lo*hi (lo*lo dropped: ~2^-16 relative, harmless)
    acc0 = __builtin_amdgcn_mfma_f32_16x16x32_bf16(ah0, b0h0, acc0, 0, 0, 0);
    acc0 = __builtin_amdgcn_mfma_f32_16x16x32_bf16(ah0, b0l0, acc0, 0, 0, 0);
    acc0 = __builtin_amdgcn_mfma_f32_16x16x32_bf16(al0, b0h0, acc0, 0, 0, 0);
    acc0 = __builtin_amdgcn_mfma_f32_16x16x32_bf16(ah1, b0h1, acc0, 0, 0, 0);
    acc0 = __builtin_amdgcn_mfma_f32_16x16x32_bf16(ah1, b0l1, acc0, 0, 0, 0);
    acc0 = __builtin_amdgcn_mfma_f32_16x16x32_bf16(al1, b0h1, acc0, 0, 0, 0);
    acc1 = __builtin_amdgcn_mfma_f32_16x16x32_bf16(ah0, b1h0, acc1, 0, 0, 0);
    acc1 = __builtin_amdgcn_mfma_f32_16x16x32_bf16(ah0, b1l0, acc1, 0, 0, 0);
    acc1 = __builtin_amdgcn_mfma_f32_16x16x32_bf16(al0, b1h0, acc1, 0, 0, 0);
    acc1 = __builtin_amdgcn_mfma_f32_16x16x32_bf16(ah1, b1h1, acc1, 0, 0, 0);
    acc1 = __builtin_amdgcn_mfma_f32_16x16x32_bf16(ah1, b1l1, acc1, 0, 0, 0);
    acc1 = __builtin_amdgcn_mfma_f32_16x16x32_bf16(al1, b1h1, acc1, 0, 0, 0);

    const float w0 = ow[b * K + c],       w1 = ow[b * K + 16 + c];
    const float q0 = nm2[b * K + c],      q1 = nm2[b * K + 16 + c];

    float rs[4];
    #pragma unroll
    for (int j = 0; j < 4; ++j) {
        const int rj = nb + wt * 16 + 4 * g + j;
        float v = 0.f;
        if (rj < N) {
            const float a = nss[rj];
            v = w0 * __expf(a + q0 + acc0[j]) + w1 * __expf(a + q1 + acc1[j]);
        }
        rs[j] = v;
    }
    // row-sum over the 16 cols (lanes within the 16-lane group)
    #pragma unroll
    for (int off = 1; off < 16; off <<= 1) {
        #pragma unroll
        for (int j = 0; j < 4; ++j) rs[j] += __shfl_xor(rs[j], off, 64);
    }
    if (c < 4) {
        const int rj = nb + wt * 16 + 4 * g + c;
        const float v = c == 0 ? rs[0] : c == 1 ? rs[1] : c == 2 ? rs[2] : rs[3];
        if (rj < N) out[b * N + rj] = v;
    }
    // wave total -> block partial
    float t4 = (rs[0] + rs[1]) + (rs[2] + rs[3]);
    t4 += __shfl_xor(t4, 16, 64);
    t4 += __shfl_xor(t4, 32, 64);
    if (lane == 0) wred[wt] = t4;
    __syncthreads();
    if (tid == 0)
        part[b * NPART + blockIdx.x] = (wred[0] + wred[1]) + (wred[2] + wred[3]);
}

// ---------------- kernel 4: normalize ----------------
__global__ void k_norm(float* __restrict__ out, const float* __restrict__ part) {
    const int b = blockIdx.y;
    const int n = blockIdx.x * 256 + threadIdx.x;
    const int tid = threadIdx.x;
    __shared__ float sdiv;
    if (tid < 64) {
        float v = 0.f;
        for (int i = tid; i < NPART; i += 64) v += part[b * NPART + i];
        #pragma unroll
        for (int off = 32; off > 0; off >>= 1) v += __shfl_down(v, off, 64);
        if (tid == 0) sdiv = 1.f / (v + 1e-10f);
    }
    __syncthreads();
    if (n < N) out[b * N + n] *= sdiv;
}

extern "C" void kernel_launch(void* const* d_in, const int* in_sizes, int n_in,
                              void* d_out, int out_size, void* d_ws, size_t ws_size,
                              hipStream_t stream) {
    const float* e   = (const float*)d_in[0];
    const float* rE  = (const float*)d_in[1];
    const float* sup = (const float*)d_in[2];
    const float* W1  = (const float*)d_in[3];
    const float* b1  = (const float*)d_in[4];
    const float* W2  = (const float*)d_in[5];
    const float* b2  = (const float*)d_in[6];
    float* out = (float*)d_out;

    char* ws = (char*)d_ws;
    int*    oidx = (int*)(ws + 0);
    float*  ow   = (float*)(ws + 2048);
    float*  nm2  = (float*)(ws + 4096);
    float*  rp   = (float*)(ws + 6144);
    ushort* tmh  = (ushort*)(ws + 38912);
    ushort* tml  = (ushort*)(ws + 104448);
    ushort* suph = (ushort*)(ws + 169984);
    ushort* supl = (ushort*)(ws + 1449984);
    float*  nss  = (float*)(ws + 2729984);
    float*  part = (float*)(ws + 2769984);

    hipLaunchKernelGGL(k_prep, dim3(N / 4), dim3(256), 0, stream,
                       sup, suph, supl, nss);
    hipLaunchKernelGGL(k_topk, dim3(B), dim3(1024), 0, stream,
                       e, rE, W1, b1, oidx, ow, rp);
    hipLaunchKernelGGL(k_means, dim3(B * 16), dim3(512), 0, stream,
                       sup, W1, W2, b2, oidx, rp, tmh, tml, nm2);
    hipLaunchKernelGGL(k_rbf, dim3(NPART, B), dim3(256), 0, stream,
                       suph, supl, tmh, tml, nss, nm2, ow, out, part);
    hipLaunchKernelGGL(k_norm, dim3(NBLK, B), dim3(256), 0, stream, out, part);
}

// Round 10
// 40.881 us; speedup vs baseline: 2.6200x; 1.1581x over previous
//
#include <hip/hip_runtime.h>
#include <hip/hip_bf16.h>

#define B 16
#define N 10000
#define D 64
#define R 64
#define H 512
#define K 32
#define NBLK ((N + 255) / 256)       // 40 (k_norm grid)
#define NPART 157                    // k_rbf grid x: 157 * 64 rows >= 10000
#define NBUCK 4096

typedef unsigned long long ull;
typedef short s16x8 __attribute__((ext_vector_type(8)));
typedef float f32x4 __attribute__((ext_vector_type(4)));

// ---------- ws layout (bytes) ----------
// oidx : B*K int      @ 0        (2048)
// ow   : B*K f32      @ 2048     (2048)
// nm2  : B*K f32      @ 4096     (2048)   -0.5*||mean||^2
// rp   : B*H f32      @ 6144     (32768)  b1 + r_b @ W1[:, :R].T
// tmh  : B*K*D bf16   @ 38912    (65536)  mean hi
// tml  : B*K*D bf16   @ 104448   (65536)  mean lo
// part : B*NPART f32  @ 169984   (10048)

static __device__ __forceinline__ ushort f2bf_bits(float x) {
    __hip_bfloat16 h = __float2bfloat16(x);
    return *reinterpret_cast<ushort*>(&h);
}
static __device__ __forceinline__ float bf_hi_f(float x) {
    return __bfloat162float(__float2bfloat16(x));
}
// split 8 floats (two float4) into bf16 hi / lo fragments
static __device__ __forceinline__ void split8(const float4 a, const float4 b,
                                              s16x8& hi, s16x8& lo) {
    const float v[8] = {a.x, a.y, a.z, a.w, b.x, b.y, b.z, b.w};
    #pragma unroll
    for (int i = 0; i < 8; ++i) {
        const ushort h = f2bf_bits(v[i]);
        const float hf = __uint_as_float(((unsigned)h) << 16);
        hi[i] = (short)h;
        lo[i] = (short)f2bf_bits(v[i] - hf);
    }
}

// ---------------- kernel 1: exact top-K set + r_part ----------------
// Top-k SET via histogram select (downstream is sum over k -> order
// irrelevant; rank gives value-determined slots; key = val_bits<<32 | ~idx
// preserves jax's smaller-index tie-break). e loaded as float4 (coalesced).
__global__ __launch_bounds__(1024) void k_topk(const float* __restrict__ e,
                                               const float* __restrict__ rE,
                                               const float* __restrict__ W1,
                                               const float* __restrict__ b1,
                                               int* __restrict__ oidx,
                                               float* __restrict__ ow,
                                               float* __restrict__ rp) {
    const int b = blockIdx.x, tid = threadIdx.x;
    __shared__ unsigned hist[NBUCK];
    __shared__ ull cand[1024];
    __shared__ float rEs[R];
    __shared__ unsigned cnt;
    __shared__ int tsh;

    #pragma unroll
    for (int i = 0; i < NBUCK / 1024; ++i) hist[tid + i * 1024] = 0;
    if (tid == 0) cnt = 0;
    if (tid < R) rEs[tid] = rE[b * R + tid];

    // 2500 float4 cover the 10000 elems exactly; 3 vec-loads per thread
    ull keys[12];
    int bkt[12];
    const float4* e4 = (const float4*)(e + b * N);
    #pragma unroll
    for (int i = 0; i < 3; ++i) {
        const int fi = tid + i * 1024;
        #pragma unroll
        for (int j = 0; j < 4; ++j) { keys[i * 4 + j] = 0ull; bkt[i * 4 + j] = -1; }
        if (fi < 2500) {
            const float4 v4 = e4[fi];
            const float vv[4] = {v4.x, v4.y, v4.z, v4.w};
            #pragma unroll
            for (int j = 0; j < 4; ++j) {
                const int n = fi * 4 + j;
                keys[i * 4 + j] = ((ull)__float_as_uint(vv[j]) << 32) |
                                  (unsigned)(0xFFFFFFFFu - (unsigned)n);
                int bu = (int)(vv[j] * (float)NBUCK);
                bkt[i * 4 + j] = bu > NBUCK - 1 ? NBUCK - 1 : (bu < 0 ? 0 : bu);
            }
        }
    }
    __syncthreads();
    #pragma unroll
    for (int i = 0; i < 12; ++i) if (bkt[i] >= 0) atomicAdd(&hist[bkt[i]], 1u);
    __syncthreads();

    // wave 0: parallel suffix scan from the top, 64 buckets per step
    if (tid < 64) {
        unsigned acc = 0;
        for (int w = 0; w < NBUCK / 64; ++w) {
            const int j = NBUCK - 1 - (w * 64 + tid);
            unsigned p = hist[j];
            #pragma unroll
            for (int off = 1; off < 64; off <<= 1) {
                unsigned o = __shfl_up(p, off, 64);
                if (tid >= off) p += o;
            }
            const ull mask = __ballot(acc + p >= K);
            if (mask) {
                if (tid == 0) {
                    const int l0 = __ffsll((long long)mask) - 1;
                    tsh = NBUCK - 1 - (w * 64 + l0);
                }
                break;
            }
            acc += (unsigned)__shfl((int)p, 63, 64);
        }
    }
    __syncthreads();
    const int t = tsh;

    #pragma unroll
    for (int i = 0; i < 12; ++i)
        if (bkt[i] >= t) {
            unsigned p = atomicAdd(&cnt, 1u);
            if (p < 1024u) cand[p] = keys[i];
        }
    __syncthreads();

    const unsigned C = cnt < 1024u ? cnt : 1024u;
    if (tid < (int)C) {
        const ull mine = cand[tid];
        int rank = 0;
        for (unsigned j = 0; j < C; ++j) rank += (cand[j] > mine);
        if (rank < K) {
            oidx[b * K + rank] = (int)(0xFFFFFFFFu - (unsigned)(mine & 0xFFFFFFFFu));
            ow[b * K + rank] = __uint_as_float((unsigned)(mine >> 32));
        }
    }

    // r_part tail (independent of selection; rEs was written pre-barrier)
    if (tid < H) {
        const float4* w = (const float4*)(W1 + tid * (R + D));  // cols 0..R
        float acc = b1[tid];
        #pragma unroll
        for (int i = 0; i < R / 4; ++i) {
            const float4 wv = w[i];
            acc += wv.x * rEs[4 * i] + wv.y * rEs[4 * i + 1] +
                   wv.z * rEs[4 * i + 2] + wv.w * rEs[4 * i + 3];
        }
        rp[b * H + tid] = acc;
    }
}

// ---------------- kernel 2: MLP on selected rows (2 pairs/block) ----------------
// writes mean as bf16 hi/lo (for MFMA) + nm2 = -0.5*||mean||^2 (f32, exact).
__global__ __launch_bounds__(512) void k_means(
        const float* __restrict__ sup, const float* __restrict__ W1,
        const float* __restrict__ W2, const float* __restrict__ b2,
        const int* __restrict__ oidx, const float* __restrict__ rp,
        ushort* __restrict__ tmh, ushort* __restrict__ tml,
        float* __restrict__ nm2) {
    const int b = blockIdx.x >> 4, pr = blockIdx.x & 15;
    const int gk = b * K + pr * 2;
    const int tid = threadIdx.x;
    __shared__ float sA[D], sB[D];
    __shared__ float hA[H], hB[H];
    __shared__ float partA[512], partB[512];

    const int id0 = oidx[gk], id1 = oidx[gk + 1];
    if (tid < D) sA[tid] = sup[id0 * D + tid];
    else if (tid < 2 * D) sB[tid - D] = sup[id1 * D + (tid - D)];
    __syncthreads();

    {   // phase 1: one h-row per thread, weight row read once for both pairs
        const float4* w = (const float4*)(W1 + tid * (R + D) + R);
        float a0 = rp[b * H + tid], a1 = a0;
        #pragma unroll
        for (int i = 0; i < D / 4; ++i) {
            const float4 wv = w[i];
            a0 += wv.x * sA[4 * i] + wv.y * sA[4 * i + 1] +
                  wv.z * sA[4 * i + 2] + wv.w * sA[4 * i + 3];
            a1 += wv.x * sB[4 * i] + wv.y * sB[4 * i + 1] +
                  wv.z * sB[4 * i + 2] + wv.w * sB[4 * i + 3];
        }
        hA[tid] = fmaxf(a0, 0.f);
        hB[tid] = fmaxf(a1, 0.f);
    }
    __syncthreads();

    {   // phase 2: d = tid&63, 8 chunks of 64 over H
        const int d = tid & 63, ch = tid >> 6;
        const float4* w2 = (const float4*)(W2 + d * H + ch * 64);
        float a0 = 0.f, a1 = 0.f;
        #pragma unroll
        for (int i = 0; i < 16; ++i) {
            const float4 wv = w2[i];
            const int hb = ch * 64 + 4 * i;
            a0 += wv.x * hA[hb] + wv.y * hA[hb + 1] + wv.z * hA[hb + 2] + wv.w * hA[hb + 3];
            a1 += wv.x * hB[hb] + wv.y * hB[hb + 1] + wv.z * hB[hb + 2] + wv.w * hB[hb + 3];
        }
        partA[tid] = a0;
        partB[tid] = a1;
    }
    __syncthreads();

    if (tid < 128) {            // wave 0 -> pair 0, wave 1 -> pair 1
        const int d = tid & 63, w = tid >> 6;
        const float* part = w == 0 ? partA : partB;
        float m = b2[d];
        #pragma unroll
        for (int c = 0; c < 8; ++c) m += part[c * 64 + d];
        const float hf = bf_hi_f(m);
        tmh[(gk + w) * D + d] = f2bf_bits(m);
        tml[(gk + w) * D + d] = f2bf_bits(m - hf);
        float sq = m * m;
        #pragma unroll
        for (int off = 32; off > 0; off >>= 1) sq += __shfl_down(sq, off, 64);
        if (d == 0) nm2[gk + w] = -0.5f * sq;
    }
}

// ---------------- kernel 3: RBF via split-bf16 MFMA, in-register sup split ----
// block = 4 waves x 16 rows = 64 n-rows, one b. Per wave: C[16n x 32k] via
// 2 coltiles x 2 d-steps x 3 split products = 12 mfma_f32_16x16x32_bf16.
// sup loaded f32 and split hi/lo in-register; row norm -0.5*||s||^2 computed
// in-wave (4 g-lanes of a row cover all 64 d; shfl_xor 16/32 reduces).
__global__ __launch_bounds__(256) void k_rbf(
        const float* __restrict__ sup,
        const ushort* __restrict__ tmh, const ushort* __restrict__ tml,
        const float* __restrict__ nm2, const float* __restrict__ ow,
        float* __restrict__ out, float* __restrict__ part) {
    const int b = blockIdx.y;
    const int tid = threadIdx.x;
    const int lane = tid & 63;
    const int wt = tid >> 6;
    const int nb = blockIdx.x * 64;
    const int g = lane >> 4;
    const int c = lane & 15;
    __shared__ float wred[4];

    // A fragments: row = nb + wt*16 + c, d-halves [g*8, g*8+8) and +32
    const int arow = nb + wt * 16 + c;
    const int arowc = arow < N ? arow : N - 1;
    const float4* sp0 = (const float4*)(sup + arowc * D + g * 8);
    const float4* sp1 = (const float4*)(sup + arowc * D + g * 8 + 32);
    const float4 f0 = sp0[0], f1 = sp0[1];
    const float4 f2 = sp1[0], f3 = sp1[1];
    s16x8 ah0, al0, ah1, al1;
    split8(f0, f1, ah0, al0);
    split8(f2, f3, ah1, al1);

    // in-wave row norm: this thread's 16 d + xor over g-bits (lanes 16,32)
    float s2 = f0.x * f0.x + f0.y * f0.y + f0.z * f0.z + f0.w * f0.w
             + f1.x * f1.x + f1.y * f1.y + f1.z * f1.z + f1.w * f1.w
             + f2.x * f2.x + f2.y * f2.y + f2.z * f2.z + f2.w * f2.w
             + f3.x * f3.x + f3.y * f3.y + f3.z * f3.z + f3.w * f3.w;
    s2 += __shfl_xor(s2, 16, 64);
    s2 += __shfl_xor(s2, 32, 64);
    const float ns2 = -0.5f * s2;          // row wt*16 + c

    // B fragments (m cols): coltile 0 -> k=c, coltile 1 -> k=16+c
    const ushort* pb0h = tmh + (b * K + c) * D + g * 8;
    const ushort* pb0l = tml + (b * K + c) * D + g * 8;
    const ushort* pb1h = pb0h + 16 * D;
    const ushort* pb1l = pb0l + 16 * D;
    const s16x8 b0h0 = *(const s16x8*)(pb0h);
    const s16x8 b0h1 = *(const s16x8*)(pb0h + 32);
    const s16x8 b0l0 = *(const s16x8*)(pb0l);
    const s16x8 b0l1 = *(const s16x8*)(pb0l + 32);
    const s16x8 b1h0 = *(const s16x8*)(pb1h);
    const s16x8 b1h1 = *(const s16x8*)(pb1h + 32);
    const s16x8 b1l0 = *(const s16x8*)(pb1l);
    const s16x8 b1l1 = *(const s16x8*)(pb1l + 32);

    f32x4 acc0 = {0.f, 0.f, 0.f, 0.f};
    f32x4 acc1 = {0.f, 0.f, 0.f, 0.f};
    // hi*hi + hi*lo + lo*hi (lo*lo dropped: ~2^-16 relative, harmless)
    acc0 = __builtin_amdgcn_mfma_f32_16x16x32_bf16(ah0, b0h0, acc0, 0, 0, 0);
    acc0 = __builtin_amdgcn_mfma_f32_16x16x32_bf16(ah0, b0l0, acc0, 0, 0, 0);
    acc0 = __builtin_amdgcn_mfma_f32_16x16x32_bf16(al0, b0h0, acc0, 0, 0, 0);
    acc0 = __builtin_amdgcn_mfma_f32_16x16x32_bf16(ah1, b0h1, acc0, 0, 0, 0);
    acc0 = __builtin_amdgcn_mfma_f32_16x16x32_bf16(ah1, b0l1, acc0, 0, 0, 0);
    acc0 = __builtin_amdgcn_mfma_f32_16x16x32_bf16(al1, b0h1, acc0, 0, 0, 0);
    acc1 = __builtin_amdgcn_mfma_f32_16x16x32_bf16(ah0, b1h0, acc1, 0, 0, 0);
    acc1 = __builtin_amdgcn_mfma_f32_16x16x32_bf16(ah0, b1l0, acc1, 0, 0, 0);
    acc1 = __builtin_amdgcn_mfma_f32_16x16x32_bf16(al0, b1h0, acc1, 0, 0, 0);
    acc1 = __builtin_amdgcn_mfma_f32_16x16x32_bf16(ah1, b1h1, acc1, 0, 0, 0);
    acc1 = __builtin_amdgcn_mfma_f32_16x16x32_bf16(ah1, b1l1, acc1, 0, 0, 0);
    acc1 = __builtin_amdgcn_mfma_f32_16x16x32_bf16(al1, b1h1, acc1, 0, 0, 0);

    const float w0 = ow[b * K + c],  w1 = ow[b * K + 16 + c];
    const float q0 = nm2[b * K + c], q1 = nm2[b * K + 16 + c];

    // C/D row j lives at rows 4*g + j; fetch its norm from lane 4*g+j (c'=4g+j)
    float nsrow[4];
    #pragma unroll
    for (int j = 0; j < 4; ++j) nsrow[j] = __shfl(ns2, 4 * g + j, 64);

    float rs[4];
    #pragma unroll
    for (int j = 0; j < 4; ++j) {
        const int rj = nb + wt * 16 + 4 * g + j;
        float v = 0.f;
        if (rj < N)
            v = w0 * __expf(nsrow[j] + q0 + acc0[j]) +
                w1 * __expf(nsrow[j] + q1 + acc1[j]);
        rs[j] = v;
    }
    // row-sum over the 16 cols (lanes within the 16-lane group)
    #pragma unroll
    for (int off = 1; off < 16; off <<= 1) {
        #pragma unroll
        for (int j = 0; j < 4; ++j) rs[j] += __shfl_xor(rs[j], off, 64);
    }
    if (c < 4) {
        const int rj = nb + wt * 16 + 4 * g + c;
        const float v = c == 0 ? rs[0] : c == 1 ? rs[1] : c == 2 ? rs[2] : rs[3];
        if (rj < N) out[b * N + rj] = v;
    }
    // wave total -> block partial
    float t4 = (rs[0] + rs[1]) + (rs[2] + rs[3]);
    t4 += __shfl_xor(t4, 16, 64);
    t4 += __shfl_xor(t4, 32, 64);
    if (lane == 0) wred[wt] = t4;
    __syncthreads();
    if (tid == 0)
        part[b * NPART + blockIdx.x] = (wred[0] + wred[1]) + (wred[2] + wred[3]);
}

// ---------------- kernel 4: normalize ----------------
__global__ void k_norm(float* __restrict__ out, const float* __restrict__ part) {
    const int b = blockIdx.y;
    const int n = blockIdx.x * 256 + threadIdx.x;
    const int tid = threadIdx.x;
    __shared__ float sdiv;
    if (tid < 64) {
        float v = 0.f;
        for (int i = tid; i < NPART; i += 64) v += part[b * NPART + i];
        #pragma unroll
        for (int off = 32; off > 0; off >>= 1) v += __shfl_down(v, off, 64);
        if (tid == 0) sdiv = 1.f / (v + 1e-10f);
    }
    __syncthreads();
    if (n < N) out[b * N + n] *= sdiv;
}

extern "C" void kernel_launch(void* const* d_in, const int* in_sizes, int n_in,
                              void* d_out, int out_size, void* d_ws, size_t ws_size,
                              hipStream_t stream) {
    const float* e   = (const float*)d_in[0];
    const float* rE  = (const float*)d_in[1];
    const float* sup = (const float*)d_in[2];
    const float* W1  = (const float*)d_in[3];
    const float* b1  = (const float*)d_in[4];
    const float* W2  = (const float*)d_in[5];
    const float* b2  = (const float*)d_in[6];
    float* out = (float*)d_out;

    char* ws = (char*)d_ws;
    int*    oidx = (int*)(ws + 0);
    float*  ow   = (float*)(ws + 2048);
    float*  nm2  = (float*)(ws + 4096);
    float*  rp   = (float*)(ws + 6144);
    ushort* tmh  = (ushort*)(ws + 38912);
    ushort* tml  = (ushort*)(ws + 104448);
    float*  part = (float*)(ws + 169984);

    hipLaunchKernelGGL(k_topk, dim3(B), dim3(1024), 0, stream,
                       e, rE, W1, b1, oidx, ow, rp);
    hipLaunchKernelGGL(k_means, dim3(B * 16), dim3(512), 0, stream,
                       sup, W1, W2, b2, oidx, rp, tmh, tml, nm2);
    hipLaunchKernelGGL(k_rbf, dim3(NPART, B), dim3(256), 0, stream,
                       sup, tmh, tml, nm2, ow, out, part);
    hipLaunchKernelGGL(k_norm, dim3(NBLK, B), dim3(256), 0, stream, out, part);
}